// Round 16
// baseline (627.841 us; speedup 1.0000x reference)
//
#include <hip/hip_runtime.h>
#include <math.h>

typedef _Float16 f16;
typedef _Float16 f16x4v __attribute__((ext_vector_type(4)));
typedef _Float16 f16x8 __attribute__((ext_vector_type(8)));
typedef float f32x4 __attribute__((ext_vector_type(4)));

#define NB 16      // batch
#define NT 16      // time steps
#define NH 64
#define NW 64
#define NF 64      // features
#define NG 256     // 4*F
#define HWF ((size_t)NH * NW * NF)          // 262144
#define OUT_BSTRIDE ((size_t)NT * HWF)      // d_out batch stride
#define RS2 8448                            // LDS row stride = 66 * 128 B (x-padded)
#define WSTEP ((size_t)18432)               // per-step wf2 size in f16x8 chunks (hi-only)
#define FSTR 16                             // ints per flag slot (64B)

#define MFMA(a, b, c) __builtin_amdgcn_mfma_f32_16x16x32_f16((a), (b), (c), 0, 0, 0)

__device__ __forceinline__ void gload_lds16(const void* g, void* l) {
    __builtin_amdgcn_global_load_lds(
        (const __attribute__((address_space(1))) unsigned int*)(g),
        (__attribute__((address_space(3))) unsigned int*)(l), 16, 0, 0);
}

__device__ __forceinline__ float hsig(float x) {
    return fminf(fmaxf(0.2f * x + 0.5f, 0.0f), 1.0f);
}

// fast tanh via v_exp_f32 (rounds 8-15 verified absmax-neutral)
__device__ __forceinline__ float ftanh(float x) {
    float t = __builtin_amdgcn_exp2f(x * 2.885390081777927f);
    return 1.0f - 2.0f * __builtin_amdgcn_rcpf(t + 1.0f);
}

// ---- prologue 1: fuse W+U -> f16 (hi only), lane-ordered, GATE-MAJOR blocks
__global__ void fuse_w_hi(const float* __restrict__ k, const float* __restrict__ rk,
                          f16* __restrict__ wf2) {
    int idx = blockIdx.x * 256 + threadIdx.x;      // over 16*9*256*8 = 294912
    if (idx >= NT * 9 * NG * 8) return;
    int g8   = idx & 7;
    int cout = (idx >> 3) & 255;
    int tt   = idx >> 11;          // t*9 + tap
    int tap  = tt % 9;
    int t    = tt / 9;
    int kk = g8 >> 2, lg = g8 & 3;

    const float* ks = k  + (size_t)tt * NF * NG + cout;
    const float* rs = rk + (size_t)tt * NF * NG + cout;

    f16 hi8[8];
#pragma unroll
    for (int j = 0; j < 8; ++j) {
        int cin = kk * 32 + lg * 8 + j;
        hi8[j] = (f16)(ks[(size_t)cin * NG] + rs[(size_t)cin * NG]);
    }
    const int lane = lg * 16 + (cout & 15);
    const int cb   = ((cout >> 4) & 3) * 4 + (cout >> 6);   // gate-major permute
    size_t chunk = (size_t)t * WSTEP + (size_t)(tap * 2 + kk) * 1024 +
                   (size_t)cb * 64 + lane;
    *(f16x8*)&wf2[chunk * 8] = *(f16x8*)hi8;
}

// ---- prologue 2: f32 -> f16 vectorized converter
__global__ void f32_to_f16(const float* __restrict__ src, f16* __restrict__ dst, int n4) {
    int i = blockIdx.x * 256 + threadIdx.x;
    if (i >= n4) return;
    float4 v = ((const float4*)src)[i];
    f16x4v o = { (f16)v.x, (f16)v.y, (f16)v.z, (f16)v.w };
    *(f16x4v*)&dst[(size_t)i * 4] = o;
}

// ---- prologue 3: zero sync flags (every launch — determinism)
__global__ void zero_flags(int* __restrict__ flags) {
    flags[blockIdx.x * 256 + threadIdx.x] = 0;     // 65536 ints
}

// ================= persistent 16-step kernel =================
// 256 blocks (1/CU), 512 thr = 8 waves (2m x 4n). Block owns (bb, 4-row slab)
// for ALL steps: c in f32 registers, own-row h in LDS. Per step only the 2
// edge rows cross blocks, via sc0sc1 (device-scope) stores/loads through L3 +
// relaxed system-scope flags. NO fences -> no L2 flush (round-7 lesson).
__global__ void __launch_bounds__(512, 2)
convlstm_persist(const f16* __restrict__ wf2,
                 const f16* __restrict__ h2init,
                 f16* __restrict__ e0, f16* __restrict__ e1,  // edge parity buffers
                 const float* __restrict__ c0,
                 float* __restrict__ out,
                 const float* __restrict__ bias_all,
                 int* __restrict__ flags)
{
    __shared__ __align__(16) unsigned char lds[6 * RS2];   // 50688 B

    const int tid  = threadIdx.x;
    const int w    = tid >> 6;
    const int lane = tid & 63;

    const int id = blockIdx.x;
    const int bb = ((id & 7) << 1) + ((id >> 7) & 1);   // batch-sticky XCD decode
    const int iy = (id >> 3) & 15;
    const int y0 = iy * 4;

    const int wm = w >> 2, wn = w & 3, lm = lane & 15, lg = lane >> 4;
    const int f  = wn * 16 + lm;

    // zero pad columns tx=0,65 (persist all steps; OOB slots 0/5 likewise)
    if (tid < 96) {
        int row = tid >> 4, side = (tid >> 3) & 1, j = tid & 7;
        *(f16x8*)&lds[row * RS2 + side * (65 * 128) + j * 16] = (f16x8)(_Float16)0.0f;
    }
    // t=0: stage all 6 rows from h2init
    {
        const int x = w * 8 + (lane >> 3);
        const int g = lane & 7;
        const unsigned src = ((unsigned)x << 7) +
                             ((unsigned)(g ^ ((x + 1) & 7)) << 4);
#pragma unroll
        for (int k = 0; k < 6; ++k) {
            const int gy = y0 - 1 + k;
            const unsigned dbase = k * RS2 + 128 + w * 1024;
            if (gy >= 0 && gy < NH) {
                const unsigned char* gsrc = (const unsigned char*)h2init +
                    ((((size_t)bb * NH + gy) * NW) << 7);
                gload_lds16(gsrc + src, (void*)&lds[dbase]);
            } else {
                *(f16x8*)&lds[dbase + lane * 16] = (f16x8)(_Float16)0.0f;
            }
        }
    }

    // c0 -> f32 registers (owned forever)
    float cp[8][4];
#pragma unroll
    for (int mf = 0; mf < 8; ++mf) {
        const int gy = y0 + wm * 2 + (mf >> 2);
        const int xb = (mf & 3) * 16 + lg * 4;
        const size_t base = ((((size_t)bb * NH + gy) * NW + xb) << 6) + f;
#pragma unroll
        for (int j = 0; j < 4; ++j) cp[mf][j] = c0[base + (size_t)j * 64];
    }

    unsigned av[3][2];
#pragma unroll
    for (int d = 0; d < 3; ++d)
#pragma unroll
        for (int kk = 0; kk < 2; ++kk) {
            const int tx = lm + d;
            av[d][kk] = (unsigned)(tx * 128 + (((kk * 4 + lg) ^ (tx & 7)) << 4));
        }

    __syncthreads();

#pragma unroll 1
    for (int t = 0; t < NT; ++t) {
        const f16x8* wb = (const f16x8*)(wf2 + (size_t)t * WSTEP * 8) +
                          (size_t)(wn * 4) * 64 + lane;
        const float* bias = bias_all + t * NG;

        // ---------- K loop (round-15 proven body)
        f32x4 acc[8][4];
#pragma unroll
        for (int mf = 0; mf < 8; ++mf)
#pragma unroll
            for (int nf = 0; nf < 4; ++nf) acc[mf][nf] = (f32x4)0.0f;

        f16x8 bh[4];
#pragma unroll
        for (int it = 0; it < 18; ++it) {
#pragma unroll
            for (int nf = 0; nf < 4; ++nf)
                bh[nf] = wb[(size_t)it * 1024 + nf * 64];
            const int tap = it >> 1, kk = it & 1;
            const int ty = tap / 3;
            const int d  = tap - ty * 3;
            const unsigned abase = (unsigned)((wm * 2 + ty) * RS2) + av[d][kk];
#pragma unroll
            for (int mf = 0; mf < 8; ++mf) {
                const f16x8 ah = *(const f16x8*)&lds[abase + (mf >> 2) * RS2 +
                                                     (mf & 3) * 2048];
#pragma unroll
                for (int nf = 0; nf < 4; ++nf)
                    acc[mf][nf] = MFMA(ah, bh[nf], acc[mf][nf]);
            }
        }

        __syncthreads();    // all A reads done before own-row overwrite

        // ---------- epilogue: in-register LSTM; h -> LDS own slots + sc1 edges
        const float b0 = bias[f], b1 = bias[64 + f], b2 = bias[128 + f], b3 = bias[192 + f];
        f16* eW = (t & 1) ? e1 : e0;
        const bool last = (t == NT - 1);

#pragma unroll
        for (int mf = 0; mf < 8; ++mf) {
            const int gy = y0 + wm * 2 + (mf >> 2);
            const int xb = (mf & 3) * 16 + lg * 4;
            const bool isEdge = (wm == 0) ? (mf < 4) : (mf >= 4);  // gy==y0 / y0+3
#pragma unroll
            for (int j = 0; j < 4; ++j) {
                const float zi  = acc[mf][0][j] + b0;
                const float zfv = acc[mf][1][j] + b1;
                const float zc  = acc[mf][2][j] + b2;
                const float zo  = acc[mf][3][j] + b3;
                const float ig = hsig(zi), fg = hsig(zfv), og = hsig(zo);
                const float cn = fg * cp[mf][j] + ig * ftanh(zc);
                cp[mf][j] = cn;
                const float hn = og * ftanh(cn);
                out[(size_t)bb * OUT_BSTRIDE + (size_t)t * HWF +
                    (((size_t)gy * NW + xb + j) << 6) + f] = hn;
                if (!last) {
                    f16 hv = (f16)hn;
                    const int x = xb + j;
                    const unsigned loff = (unsigned)((wm * 2 + (mf >> 2) + 1) * RS2 +
                        128 + x * 128 + (((f >> 3) ^ ((x + 1) & 7)) << 4) + (f & 7) * 2);
                    *(f16*)&lds[loff] = hv;            // own-row h into A-buffer
                    if (isEdge) {                       // device-scope edge publish
                        const f16* ep = eW + ((((size_t)bb * NH + gy) * NW + x) << 6) + f;
                        int hb = (int)*(unsigned short*)&hv;
                        asm volatile("global_store_short %0, %1, off sc0 sc1"
                                     :: "v"(ep), "v"(hb) : "memory");
                    }
                }
            }
        }

        if (!last) {
            __syncthreads();   // drains vmcnt(0): edge stores acked at L3; ds done

            if (tid == 0) {
                const int fbase = ((t * NB + bb) * 16) * FSTR;
                __hip_atomic_store(&flags[fbase + iy * FSTR], 1,
                                   __ATOMIC_RELAXED, __HIP_MEMORY_SCOPE_SYSTEM);
                if (iy > 0)
                    while (__hip_atomic_load(&flags[fbase + (iy - 1) * FSTR],
                           __ATOMIC_RELAXED, __HIP_MEMORY_SCOPE_SYSTEM) == 0)
                        __builtin_amdgcn_s_sleep(1);
                if (iy < 15)
                    while (__hip_atomic_load(&flags[fbase + (iy + 1) * FSTR],
                           __ATOMIC_RELAXED, __HIP_MEMORY_SCOPE_SYSTEM) == 0)
                        __builtin_amdgcn_s_sleep(1);
            }
            __syncthreads();

            // halo refill: rows y0-1 (slot 0) and y0+4 (slot 5) from eW via L3
            const int gi0 = tid * 2;            // 0..1022 even; pair shares row r
            const int r   = gi0 >> 9;
            const bool valid = r ? (iy < 15) : (iy > 0);
            if (valid) {
                const int gy = r ? (y0 + 4) : (y0 - 1);
                const int rem0 = gi0 & 511, rem1 = rem0 + 1;
                const int x0 = rem0 >> 3, g0 = rem0 & 7;
                const int x1 = rem1 >> 3, g1 = rem1 & 7;
                const f16* sp0 = eW + ((((size_t)bb * NH + gy) * NW + x0) << 6) + g0 * 8;
                const f16* sp1 = eW + ((((size_t)bb * NH + gy) * NW + x1) << 6) + g1 * 8;
                f16x8 v0, v1;
                asm volatile("global_load_dwordx4 %0, %1, off sc0 sc1"
                             : "=v"(v0) : "v"(sp0) : "memory");
                asm volatile("global_load_dwordx4 %0, %1, off sc0 sc1"
                             : "=v"(v1) : "v"(sp1) : "memory");
                asm volatile("s_waitcnt vmcnt(0)" ::: "memory");
                const unsigned slot = (r ? 5u : 0u) * RS2 + 128;
                unsigned d0 = (unsigned)(uintptr_t)&lds[slot + x0 * 128 +
                                                        ((g0 ^ ((x0 + 1) & 7)) << 4)];
                unsigned d1 = (unsigned)(uintptr_t)&lds[slot + x1 * 128 +
                                                        ((g1 ^ ((x1 + 1) & 7)) << 4)];
                asm volatile("ds_write_b128 %0, %1" :: "v"(d0), "v"(v0) : "memory");
                asm volatile("ds_write_b128 %0, %1" :: "v"(d1), "v"(v1) : "memory");
            }
            __syncthreads();
        }
    }
}

// ================= fallback: round-15 one-step kernel (proven) =================
__global__ void __launch_bounds__(512, 2)
convlstm_mfma_step(const f16* __restrict__ h2in, f16* __restrict__ h2out,
                   f16* __restrict__ cbuf, float* __restrict__ hout,
                   const f16* __restrict__ wt, const float* __restrict__ bias)
{
    __shared__ __align__(16) unsigned char lds[6 * RS2];

    const int tid  = threadIdx.x;
    const int w    = tid >> 6;
    const int lane = tid & 63;
    const int id = blockIdx.x;
    const int bb = ((id & 7) << 1) + ((id >> 7) & 1);
    const int y0 = ((id >> 3) & 15) * 4;
    const int wm = w >> 2, wn = w & 3, lm = lane & 15, lg = lane >> 4;

    const f16x8* wb = (const f16x8*)wt + (size_t)(wn * 4) * 64 + lane;
    f16x8 bh[4];
#pragma unroll
    for (int nf = 0; nf < 4; ++nf) bh[nf] = wb[nf * 64];

    const int f = wn * 16 + lm;
    f16 cp[8][4];
#pragma unroll
    for (int mf = 0; mf < 8; ++mf) {
        const int gy = y0 + wm * 2 + (mf >> 2);
        const int xb = (mf & 3) * 16 + lg * 4;
        const size_t base = ((((size_t)bb * NH + gy) * NW + xb) << 6) + f;
#pragma unroll
        for (int j = 0; j < 4; ++j) cp[mf][j] = cbuf[base + (size_t)j * 64];
    }

    if (tid < 96) {
        int row = tid >> 4, side = (tid >> 3) & 1, j = tid & 7;
        *(f16x8*)&lds[row * RS2 + side * (65 * 128) + j * 16] = (f16x8)(_Float16)0.0f;
    }
    {
        const int x = w * 8 + (lane >> 3);
        const int g = lane & 7;
        const unsigned src = ((unsigned)x << 7) +
                             ((unsigned)(g ^ ((x + 1) & 7)) << 4);
#pragma unroll
        for (int k = 0; k < 6; ++k) {
            const int gy = y0 - 1 + k;
            const unsigned dbase = k * RS2 + 128 + w * 1024;
            if (gy >= 0 && gy < NH) {
                const unsigned char* gsrc = (const unsigned char*)h2in +
                    ((((size_t)bb * NH + gy) * NW) << 7);
                gload_lds16(gsrc + src, (void*)&lds[dbase]);
            } else {
                *(f16x8*)&lds[dbase + lane * 16] = (f16x8)(_Float16)0.0f;
            }
        }
    }
    __syncthreads();

    f32x4 acc[8][4];
#pragma unroll
    for (int mf = 0; mf < 8; ++mf)
#pragma unroll
        for (int nf = 0; nf < 4; ++nf) acc[mf][nf] = (f32x4)0.0f;

    unsigned av[3][2];
#pragma unroll
    for (int d = 0; d < 3; ++d)
#pragma unroll
        for (int kk = 0; kk < 2; ++kk) {
            const int tx = lm + d;
            av[d][kk] = (unsigned)(tx * 128 + (((kk * 4 + lg) ^ (tx & 7)) << 4));
        }

#pragma unroll
    for (int it = 0; it < 18; ++it) {
        if (it > 0) {
#pragma unroll
            for (int nf = 0; nf < 4; ++nf)
                bh[nf] = wb[(size_t)it * 1024 + nf * 64];
        }
        const int tap = it >> 1, kk = it & 1;
        const int ty = tap / 3;
        const int d  = tap - ty * 3;
        const unsigned abase = (unsigned)((wm * 2 + ty) * RS2) + av[d][kk];
#pragma unroll
        for (int mf = 0; mf < 8; ++mf) {
            const f16x8 ah = *(const f16x8*)&lds[abase + (mf >> 2) * RS2 +
                                                 (mf & 3) * 2048];
#pragma unroll
            for (int nf = 0; nf < 4; ++nf)
                acc[mf][nf] = MFMA(ah, bh[nf], acc[mf][nf]);
        }
    }

    const float b0 = bias[f], b1 = bias[64 + f], b2 = bias[128 + f], b3 = bias[192 + f];
#pragma unroll
    for (int mf = 0; mf < 8; ++mf) {
        const int gy = y0 + wm * 2 + (mf >> 2);
        const int xb = (mf & 3) * 16 + lg * 4;
        const size_t base = ((((size_t)bb * NH + gy) * NW + xb) << 6) + f;
#pragma unroll
        for (int j = 0; j < 4; ++j) {
            const float zi  = acc[mf][0][j] + b0;
            const float zfv = acc[mf][1][j] + b1;
            const float zc  = acc[mf][2][j] + b2;
            const float zo  = acc[mf][3][j] + b3;
            const float ig = hsig(zi), fg = hsig(zfv), og = hsig(zo);
            const float cn = fg * (float)cp[mf][j] + ig * ftanh(zc);
            cbuf[base + (size_t)j * 64] = (f16)cn;
            const float hn = og * ftanh(cn);
            hout[(size_t)bb * OUT_BSTRIDE + (((size_t)gy * NW + xb + j) << 6) + f] = hn;
            h2out[base + (size_t)j * 64] = (f16)hn;
        }
    }
}

extern "C" void kernel_launch(void* const* d_in, const int* in_sizes, int n_in,
                              void* d_out, int out_size, void* d_ws, size_t ws_size,
                              hipStream_t stream) {
    const float* h0    = (const float*)d_in[1];
    const float* c0    = (const float*)d_in[2];
    const float* kern  = (const float*)d_in[3];
    const float* rkern = (const float*)d_in[4];
    const float* bias  = (const float*)d_in[5];
    float* out = (float*)d_out;

    f16* wf2   = (f16*)d_ws;                                  // 4.7 MB
    f16* h2a   = wf2 + (size_t)NT * WSTEP * 8;                // 8.4 MB (init h / fallback ping)
    f16* h2b   = h2a + (size_t)NB * HWF;                      // 8.4 MB (E0 / fallback pong)
    f16* e1    = h2b + (size_t)NB * HWF;                      // 8.4 MB (E1)
    f16* cbuf  = e1  + (size_t)NB * HWF;                      // 8.4 MB (fallback c)
    int* flags = (int*)(cbuf + (size_t)NB * HWF);             // 256 KB

    const int n4 = (int)(NB * HWF / 4);
    fuse_w_hi<<<(NT * 9 * NG * 8 + 255) / 256, 256, 0, stream>>>(kern, rkern, wf2);
    f32_to_f16<<<(n4 + 255) / 256, 256, 0, stream>>>(h0, h2a, n4);
    f32_to_f16<<<(n4 + 255) / 256, 256, 0, stream>>>(c0, cbuf, n4);
    zero_flags<<<256, 256, 0, stream>>>(flags);

    const f16* wf2c = wf2;
    const f16* h2ac = h2a;
    const float* c0c = c0;
    const float* biasc = bias;
    void* args[] = { (void*)&wf2c, (void*)&h2ac, (void*)&h2b, (void*)&e1,
                     (void*)&c0c, (void*)&out, (void*)&biasc, (void*)&flags };
    hipError_t ce = hipLaunchCooperativeKernel(
        (const void*)convlstm_persist, dim3(256), dim3(512), args, 0u, stream);

    if (ce != hipSuccess) {
        (void)hipGetLastError();
        for (int t = 0; t < NT; ++t) {
            const f16* hin = (t & 1) ? h2b : h2a;
            f16* hnx       = (t & 1) ? h2a : h2b;
            convlstm_mfma_step<<<dim3(256), 512, 0, stream>>>(
                hin, hnx, cbuf,
                out + (size_t)t * HWF,
                wf2 + (size_t)t * WSTEP * 8,
                bias + t * NG);
        }
    }
}

// Round 17
// 532.234 us; speedup vs baseline: 1.1796x; 1.1796x over previous
//
#include <hip/hip_runtime.h>
#include <math.h>

typedef _Float16 f16;
typedef _Float16 f16x4v __attribute__((ext_vector_type(4)));
typedef _Float16 f16x8 __attribute__((ext_vector_type(8)));
typedef float f32x4 __attribute__((ext_vector_type(4)));

#define NB 16      // batch
#define NT 16      // time steps
#define NH 64
#define NW 64
#define NF 64      // features
#define NG 256     // 4*F
#define HWF ((size_t)NH * NW * NF)          // 262144
#define OUT_BSTRIDE ((size_t)NT * HWF)      // d_out batch stride
#define RS2 8448                            // LDS row stride = 66 * 128 B (x-padded)
#define WSTEP ((size_t)18432)               // per-step wf2 size in f16x8 chunks (hi-only)

#define MFMA(a, b, c) __builtin_amdgcn_mfma_f32_16x16x32_f16((a), (b), (c), 0, 0, 0)

__device__ __forceinline__ void gload_lds16(const void* g, void* l) {
    __builtin_amdgcn_global_load_lds(
        (const __attribute__((address_space(1))) unsigned int*)(g),
        (__attribute__((address_space(3))) unsigned int*)(l), 16, 0, 0);
}

__device__ __forceinline__ float hsig(float x) {
    return fminf(fmaxf(0.2f * x + 0.5f, 0.0f), 1.0f);
}

// fast tanh via v_exp_f32 (rounds 8-15 verified absmax-neutral)
__device__ __forceinline__ float ftanh(float x) {
    float t = __builtin_amdgcn_exp2f(x * 2.885390081777927f);
    return 1.0f - 2.0f * __builtin_amdgcn_rcpf(t + 1.0f);
}

// ---- prologue 1: fuse W+U -> f16 (hi only), lane-ordered, GATE-MAJOR blocks:
// chunk (f16x8 units): (tap*2+kk)*1024 + cb*64 + lane, with
// cb = ((cout>>4)&3)*4 + (cout>>6)   [f-group major, gate minor]
__global__ void fuse_w_hi(const float* __restrict__ k, const float* __restrict__ rk,
                          f16* __restrict__ wf2) {
    int idx = blockIdx.x * 256 + threadIdx.x;      // over 16*9*256*8 = 294912
    if (idx >= NT * 9 * NG * 8) return;
    int g8   = idx & 7;
    int cout = (idx >> 3) & 255;
    int tt   = idx >> 11;          // t*9 + tap
    int tap  = tt % 9;
    int t    = tt / 9;
    int kk = g8 >> 2, lg = g8 & 3;

    const float* ks = k  + (size_t)tt * NF * NG + cout;
    const float* rs = rk + (size_t)tt * NF * NG + cout;

    f16 hi8[8];
#pragma unroll
    for (int j = 0; j < 8; ++j) {
        int cin = kk * 32 + lg * 8 + j;
        hi8[j] = (f16)(ks[(size_t)cin * NG] + rs[(size_t)cin * NG]);
    }
    const int lane = lg * 16 + (cout & 15);
    const int cb   = ((cout >> 4) & 3) * 4 + (cout >> 6);   // gate-major permute
    size_t chunk = (size_t)t * WSTEP + (size_t)(tap * 2 + kk) * 1024 +
                   (size_t)cb * 64 + lane;
    *(f16x8*)&wf2[chunk * 8] = *(f16x8*)hi8;
}

// ---- prologue 2: f32 -> f16 vectorized converter (h0 and c0)
__global__ void f32_to_f16(const float* __restrict__ src, f16* __restrict__ dst, int n4) {
    int i = blockIdx.x * 256 + threadIdx.x;
    if (i >= n4) return;
    float4 v = ((const float4*)src)[i];
    f16x4v o = { (f16)v.x, (f16)v.y, (f16)v.z, (f16)v.w };
    *(f16x4v*)&dst[(size_t)i * 4] = o;
}

// ---- one ConvLSTM step: 256 blocks (1/CU), 512 thr = 8 waves (2m x 4n).
// Block tile: 4 rows x 64 x x 256 couts; wave M=128 (2 rows) x N=64 (4 gates
// x 16 f, gate-major -> in-register LSTM epilogue, 1 barrier/step).
// K-loop restructured (kk,d)-major with rolling 3-slot A window:
// A-LDS reads 144 -> 96 per wave (-33%); B double-buffered one ty ahead.
__global__ void __launch_bounds__(512, 2)
convlstm_mfma_step(const f16* __restrict__ h2in, f16* __restrict__ h2out,
                   f16* __restrict__ cbuf,        // f16 cell state (in-place)
                   float* __restrict__ hout,        // d_out + t*HWF
                   const f16* __restrict__ wt,      // gate-major lane-ordered chunks
                   const float* __restrict__ bias)  // [256] for this t
{
    __shared__ __align__(16) unsigned char lds[6 * RS2];   // 50688 B

    const int tid  = threadIdx.x;
    const int w    = tid >> 6;
    const int lane = tid & 63;

    // batch-sticky XCD decode: id = xcd + 8*iy + 128*bhalf ; 256 blocks total
    const int id = blockIdx.x;
    const int bb = ((id & 7) << 1) + ((id >> 7) & 1);
    const int y0 = ((id >> 3) & 15) * 4;

    const int wm = w >> 2;     // 0..1 : which row-pair of the 4-row tile
    const int wn = w & 3;      // 0..3 : feature group of 16
    const int lm = lane & 15;
    const int lg = lane >> 4;

    const f16x8* wb = (const f16x8*)wt + (size_t)(wn * 4) * 64 + lane;

    // prefetch c-state (independent of staging)
    const int f = wn * 16 + lm;
    f16 cp[8][4];
#pragma unroll
    for (int mf = 0; mf < 8; ++mf) {
        const int gy = y0 + wm * 2 + (mf >> 2);
        const int xb = (mf & 3) * 16 + lg * 4;
        const size_t base = ((((size_t)bb * NH + gy) * NW + xb) << 6) + f;
#pragma unroll
        for (int j = 0; j < 4; ++j)
            cp[mf][j] = cbuf[base + (size_t)j * 64];
    }

    // zero the pad columns tx=0 and tx=65 (6 rows x 2 x 8 granules)
    if (tid < 96) {
        int row = tid >> 4, side = (tid >> 3) & 1, j = tid & 7;
        *(f16x8*)&lds[row * RS2 + side * (65 * 128) + j * 16] = (f16x8)(_Float16)0.0f;
    }

    // stage rows y0-1 .. y0+4: wave w covers x in [w*8, w*8+8) for all 6 rows
    {
        const int x = w * 8 + (lane >> 3);
        const int g = lane & 7;
        const unsigned src = ((unsigned)x << 7) +
                             ((unsigned)(g ^ ((x + 1) & 7)) << 4);
#pragma unroll
        for (int k = 0; k < 6; ++k) {
            const int gy = y0 - 1 + k;
            const unsigned dbase = k * RS2 + 128 + w * 1024;   // wave-uniform
            if (gy >= 0 && gy < NH) {
                const unsigned char* gsrc = (const unsigned char*)h2in +
                    ((((size_t)bb * NH + gy) * NW) << 7);
                gload_lds16(gsrc + src, (void*)&lds[dbase]);
            } else {
                *(f16x8*)&lds[dbase + lane * 16] = (f16x8)(_Float16)0.0f;
            }
        }
    }
    __syncthreads();        // the ONLY barrier

    // ---------- K loop: (kk,d)-major, rolling A window, 1-term f16
    f32x4 acc[8][4];
#pragma unroll
    for (int mf = 0; mf < 8; ++mf)
#pragma unroll
        for (int nf = 0; nf < 4; ++nf) acc[mf][nf] = (f32x4)0.0f;

    // per-lane swizzled A offsets: tx = lm + d, granule g = kk*4+lg, slot = g ^ (tx&7)
    unsigned av[3][2];
#pragma unroll
    for (int d = 0; d < 3; ++d)
#pragma unroll
        for (int kk = 0; kk < 2; ++kk) {
            const int tx = lm + d;
            av[d][kk] = (unsigned)(tx * 128 +
                        (((kk * 4 + lg) ^ (tx & 7)) << 4));
        }

    f16x8 A0[4], A1[4], A2[4], bh0[4], bh1[4];

#pragma unroll
    for (int kk = 0; kk < 2; ++kk)
#pragma unroll
    for (int d = 0; d < 3; ++d) {
        const unsigned abase = (unsigned)(wm * 2 * RS2) + av[d][kk];

        // B for ty=0 (tap = d)
        {
            const int it0 = d * 2 + kk;
#pragma unroll
            for (int nf = 0; nf < 4; ++nf)
                bh0[nf] = wb[(size_t)it0 * 1024 + nf * 64];
        }
        // A slots wm*2, wm*2+1
#pragma unroll
        for (int xb = 0; xb < 4; ++xb)
            A0[xb] = *(const f16x8*)&lds[abase + xb * 2048];
#pragma unroll
        for (int xb = 0; xb < 4; ++xb)
            A1[xb] = *(const f16x8*)&lds[abase + RS2 + xb * 2048];

        // ---- ty = 0 (rows wm*2, +1); prefetch B ty=1 and A slot +2
        {
            const int it1 = (3 + d) * 2 + kk;
#pragma unroll
            for (int nf = 0; nf < 4; ++nf)
                bh1[nf] = wb[(size_t)it1 * 1024 + nf * 64];
#pragma unroll
            for (int xb = 0; xb < 4; ++xb)
                A2[xb] = *(const f16x8*)&lds[abase + 2 * RS2 + xb * 2048];
            __builtin_amdgcn_s_setprio(1);
#pragma unroll
            for (int mf = 0; mf < 8; ++mf) {
                const f16x8 ah = (mf >> 2) ? A1[mf & 3] : A0[mf & 3];
#pragma unroll
                for (int nf = 0; nf < 4; ++nf)
                    acc[mf][nf] = MFMA(ah, bh0[nf], acc[mf][nf]);
            }
            __builtin_amdgcn_s_setprio(0);
        }
        // ---- ty = 1 (rows +1, +2); prefetch B ty=2 into bh0, A slot +3 into A0
        {
            const int it2 = (6 + d) * 2 + kk;
#pragma unroll
            for (int nf = 0; nf < 4; ++nf)
                bh0[nf] = wb[(size_t)it2 * 1024 + nf * 64];
#pragma unroll
            for (int xb = 0; xb < 4; ++xb)
                A0[xb] = *(const f16x8*)&lds[abase + 3 * RS2 + xb * 2048];
            __builtin_amdgcn_s_setprio(1);
#pragma unroll
            for (int mf = 0; mf < 8; ++mf) {
                const f16x8 ah = (mf >> 2) ? A2[mf & 3] : A1[mf & 3];
#pragma unroll
                for (int nf = 0; nf < 4; ++nf)
                    acc[mf][nf] = MFMA(ah, bh1[nf], acc[mf][nf]);
            }
            __builtin_amdgcn_s_setprio(0);
        }
        // ---- ty = 2 (rows +2, +3)
        {
            __builtin_amdgcn_s_setprio(1);
#pragma unroll
            for (int mf = 0; mf < 8; ++mf) {
                const f16x8 ah = (mf >> 2) ? A0[mf & 3] : A2[mf & 3];
#pragma unroll
                for (int nf = 0; nf < 4; ++nf)
                    acc[mf][nf] = MFMA(ah, bh0[nf], acc[mf][nf]);
            }
            __builtin_amdgcn_s_setprio(0);
        }
    }

    // ---------- epilogue: fully in-register LSTM pointwise
    const float b0 = bias[f], b1 = bias[64 + f], b2 = bias[128 + f], b3 = bias[192 + f];

#pragma unroll
    for (int mf = 0; mf < 8; ++mf) {
        const int gy = y0 + wm * 2 + (mf >> 2);
        const int xb = (mf & 3) * 16 + lg * 4;
        const size_t base = ((((size_t)bb * NH + gy) * NW + xb) << 6) + f;
#pragma unroll
        for (int j = 0; j < 4; ++j) {
            const float zi  = acc[mf][0][j] + b0;
            const float zfv = acc[mf][1][j] + b1;
            const float zc  = acc[mf][2][j] + b2;
            const float zo  = acc[mf][3][j] + b3;
            const float ig = hsig(zi), fg = hsig(zfv), og = hsig(zo);
            const float cn = fg * (float)cp[mf][j] + ig * ftanh(zc);
            cbuf[base + (size_t)j * 64] = (f16)cn;
            const float hn = og * ftanh(cn);
            hout[(size_t)bb * OUT_BSTRIDE + (((size_t)gy * NW + xb + j) << 6) + f] = hn;
            h2out[base + (size_t)j * 64] = (f16)hn;
        }
    }
}

extern "C" void kernel_launch(void* const* d_in, const int* in_sizes, int n_in,
                              void* d_out, int out_size, void* d_ws, size_t ws_size,
                              hipStream_t stream) {
    const float* h0    = (const float*)d_in[1];
    const float* c0    = (const float*)d_in[2];
    const float* kern  = (const float*)d_in[3];
    const float* rkern = (const float*)d_in[4];
    const float* bias  = (const float*)d_in[5];
    float* out = (float*)d_out;

    f16* wf2   = (f16*)d_ws;                                  // 4.7 MB (hi only)
    f16* h2a   = wf2 + (size_t)NT * WSTEP * 8;                // 8.4 MB
    f16* h2b   = h2a + (size_t)NB * HWF;                      // 8.4 MB
    f16* cbuf  = h2b + (size_t)NB * HWF;                      // 8.4 MB (f16 c state)

    const int n4 = (int)(NB * HWF / 4);                       // 1,048,576
    fuse_w_hi<<<(NT * 9 * NG * 8 + 255) / 256, 256, 0, stream>>>(kern, rkern, wf2);
    f32_to_f16<<<(n4 + 255) / 256, 256, 0, stream>>>(h0, h2a, n4);
    f32_to_f16<<<(n4 + 255) / 256, 256, 0, stream>>>(c0, cbuf, n4);

    for (int t = 0; t < NT; ++t) {
        const f16* hin = (t & 1) ? h2b : h2a;
        f16* hnx       = (t & 1) ? h2a : h2b;
        convlstm_mfma_step<<<dim3(256), 512, 0, stream>>>(
            hin, hnx, cbuf,
            out + (size_t)t * HWF,
            wf2 + (size_t)t * WSTEP * 8,
            bias + t * NG);
    }
}

// Round 18
// 380.601 us; speedup vs baseline: 1.6496x; 1.3984x over previous
//
#include <hip/hip_runtime.h>
#include <math.h>

typedef _Float16 f16;
typedef _Float16 f16x4v __attribute__((ext_vector_type(4)));
typedef _Float16 f16x8 __attribute__((ext_vector_type(8)));
typedef float f32x4 __attribute__((ext_vector_type(4)));

#define NB 16      // batch
#define NT 16      // time steps
#define NH 64
#define NW 64
#define NF 64      // features
#define NG 256     // 4*F
#define HWF ((size_t)NH * NW * NF)          // 262144
#define OUT_BSTRIDE ((size_t)NT * HWF)      // d_out batch stride
#define RS2 8448                            // LDS row stride = 66 * 128 B (x-padded)
#define WSTEP ((size_t)18432)               // per-step wf2 size in f16x8 chunks (hi-only)

#define MFMA(a, b, c) __builtin_amdgcn_mfma_f32_16x16x32_f16((a), (b), (c), 0, 0, 0)

__device__ __forceinline__ void gload_lds16(const void* g, void* l) {
    __builtin_amdgcn_global_load_lds(
        (const __attribute__((address_space(1))) unsigned int*)(g),
        (__attribute__((address_space(3))) unsigned int*)(l), 16, 0, 0);
}

__device__ __forceinline__ float hsig(float x) {
    return fminf(fmaxf(0.2f * x + 0.5f, 0.0f), 1.0f);
}

// fast tanh via v_exp_f32 (rounds 8-15 verified absmax-neutral)
__device__ __forceinline__ float ftanh(float x) {
    float t = __builtin_amdgcn_exp2f(x * 2.885390081777927f);
    return 1.0f - 2.0f * __builtin_amdgcn_rcpf(t + 1.0f);
}

// ================= merged prologue: one kernel, 9344 blocks ================
// blocks [0,1152): fuse W+U -> f16 hi-only, lane-ordered, gate-major
// blocks [1152,5248): h0 f32 -> f16 (layout [pos][f], matches stager)
// blocks [5248,9344): c0 f32 -> f16 TRANSPOSED to [b][y][f][x] (x-contiguous)
__global__ void prologue_all(const float* __restrict__ k, const float* __restrict__ rk,
                             f16* __restrict__ wf2,
                             const float* __restrict__ h0, f16* __restrict__ h2,
                             const float* __restrict__ c0, f16* __restrict__ cbuf) {
    const int blk = blockIdx.x;
    const int tid = threadIdx.x;

    if (blk < 1152) {
        // ---- weights: over 16*9*256*8 = 294912 threads
        int idx = blk * 256 + tid;
        int g8   = idx & 7;
        int cout = (idx >> 3) & 255;
        int tt   = idx >> 11;          // t*9 + tap
        int tap  = tt % 9;
        int t    = tt / 9;
        int kk = g8 >> 2, lg = g8 & 3;

        const float* ks = k  + (size_t)tt * NF * NG + cout;
        const float* rs = rk + (size_t)tt * NF * NG + cout;

        f16 hi8[8];
#pragma unroll
        for (int j = 0; j < 8; ++j) {
            int cin = kk * 32 + lg * 8 + j;
            hi8[j] = (f16)(ks[(size_t)cin * NG] + rs[(size_t)cin * NG]);
        }
        const int lane = lg * 16 + (cout & 15);
        const int cb   = ((cout >> 4) & 3) * 4 + (cout >> 6);   // gate-major
        size_t chunk = (size_t)t * WSTEP + (size_t)(tap * 2 + kk) * 1024 +
                       (size_t)cb * 64 + lane;
        *(f16x8*)&wf2[chunk * 8] = *(f16x8*)hi8;
    } else if (blk < 5248) {
        // ---- h0 convert: 1,048,576 threads x 4 elements
        int i = (blk - 1152) * 256 + tid;
        float4 v = ((const float4*)h0)[i];
        f16x4v o = { (f16)v.x, (f16)v.y, (f16)v.z, (f16)v.w };
        *(f16x4v*)&h2[(size_t)i * 4] = o;
    } else {
        // ---- c0 transpose-convert: t = ((bgy)*16 + x4)*64 + f
        int i = (blk - 5248) * 256 + tid;      // [0, 1048576)
        int bgy = i >> 10;
        int rem = i & 1023;
        int x4  = rem >> 6;
        int f   = rem & 63;
        const float* src = c0 + (size_t)bgy * 4096 + (size_t)x4 * 256 + f;
        f16x4v o = { (f16)src[0], (f16)src[64], (f16)src[128], (f16)src[192] };
        *(f16x4v*)&cbuf[((size_t)bgy * 64 + f) * 64 + x4 * 4] = o;
    }
}

// ---- one ConvLSTM step: round-15 proven structure. 256 blocks (1/CU),
// 512 thr = 8 waves (2m x 4n); block tile 4 rows x 64 x x 256 couts;
// gate-major B -> in-register LSTM epilogue; 1 barrier/step.
// cbuf is x-contiguous [b][y][f][x]: c load/store = f16x4 (8 ops vs 64).
__global__ void __launch_bounds__(512, 2)
convlstm_mfma_step(const f16* __restrict__ h2in, f16* __restrict__ h2out,
                   f16* __restrict__ cbuf,
                   float* __restrict__ hout,        // d_out + t*HWF
                   const f16* __restrict__ wt,
                   const float* __restrict__ bias,  // [256] for this t
                   int last)                        // t == NT-1: skip state stores
{
    __shared__ __align__(16) unsigned char lds[6 * RS2];   // 50688 B

    const int tid  = threadIdx.x;
    const int w    = tid >> 6;
    const int lane = tid & 63;

    // batch-sticky XCD decode: id = xcd + 8*iy + 128*bhalf ; 256 blocks total
    const int id = blockIdx.x;
    const int bb = ((id & 7) << 1) + ((id >> 7) & 1);
    const int y0 = ((id >> 3) & 15) * 4;

    const int wm = w >> 2;     // 0..1 : row-pair of the 4-row tile
    const int wn = w & 3;      // 0..3 : feature group of 16
    const int lm = lane & 15;
    const int lg = lane >> 4;

    const f16x8* wb = (const f16x8*)wt + (size_t)(wn * 4) * 64 + lane;

    // prefetch it=0 B fragments (independent of staging)
    f16x8 bh[4];
#pragma unroll
    for (int nf = 0; nf < 4; ++nf)
        bh[nf] = wb[nf * 64];

    // prefetch c-state: 8 x f16x4 vector loads (x-contiguous cbuf)
    const int f = wn * 16 + lm;
    f16x4v cp[8];
#pragma unroll
    for (int mf = 0; mf < 8; ++mf) {
        const int gy = y0 + wm * 2 + (mf >> 2);
        const int xb = (mf & 3) * 16 + lg * 4;
        cp[mf] = *(const f16x4v*)&cbuf[(((size_t)bb * NH + gy) * NF + f) * 64 + xb];
    }

    // zero the pad columns tx=0 and tx=65 (6 rows x 2 x 8 granules)
    if (tid < 96) {
        int row = tid >> 4, side = (tid >> 3) & 1, j = tid & 7;
        *(f16x8*)&lds[row * RS2 + side * (65 * 128) + j * 16] = (f16x8)(_Float16)0.0f;
    }

    // stage rows y0-1 .. y0+4: wave w covers x in [w*8, w*8+8) for all 6 rows
    {
        const int x = w * 8 + (lane >> 3);
        const int g = lane & 7;
        const unsigned src = ((unsigned)x << 7) +
                             ((unsigned)(g ^ ((x + 1) & 7)) << 4);
#pragma unroll
        for (int kr = 0; kr < 6; ++kr) {
            const int gy = y0 - 1 + kr;
            const unsigned dbase = kr * RS2 + 128 + w * 1024;   // wave-uniform
            if (gy >= 0 && gy < NH) {
                const unsigned char* gsrc = (const unsigned char*)h2in +
                    ((((size_t)bb * NH + gy) * NW) << 7);
                gload_lds16(gsrc + src, (void*)&lds[dbase]);
            } else {
                *(f16x8*)&lds[dbase + lane * 16] = (f16x8)(_Float16)0.0f;
            }
        }
    }
    __syncthreads();        // the ONLY barrier

    // ---------- K loop: 9 taps x 2 cin-halves, fully unrolled, 1-term f16
    f32x4 acc[8][4];
#pragma unroll
    for (int mf = 0; mf < 8; ++mf)
#pragma unroll
        for (int nf = 0; nf < 4; ++nf) acc[mf][nf] = (f32x4)0.0f;

    // per-lane swizzled A offsets: tx = lm + d, granule g = kk*4+lg, slot = g ^ (tx&7)
    unsigned av[3][2];
#pragma unroll
    for (int d = 0; d < 3; ++d)
#pragma unroll
        for (int kk = 0; kk < 2; ++kk) {
            const int tx = lm + d;
            av[d][kk] = (unsigned)(tx * 128 +
                        (((kk * 4 + lg) ^ (tx & 7)) << 4));
        }

#pragma unroll
    for (int it = 0; it < 18; ++it) {
        if (it > 0) {
#pragma unroll
            for (int nf = 0; nf < 4; ++nf)
                bh[nf] = wb[(size_t)it * 1024 + nf * 64];
        }
        const int tap = it >> 1, kk = it & 1;
        const int ty = tap / 3;
        const int d  = tap - ty * 3;
        const unsigned abase = (unsigned)((wm * 2 + ty) * RS2) + av[d][kk];
        __builtin_amdgcn_s_setprio(1);
#pragma unroll
        for (int mf = 0; mf < 8; ++mf) {
            const f16x8 ah = *(const f16x8*)&lds[abase + (mf >> 2) * RS2 +
                                                 (mf & 3) * 2048];
#pragma unroll
            for (int nf = 0; nf < 4; ++nf)
                acc[mf][nf] = MFMA(ah, bh[nf], acc[mf][nf]);
        }
        __builtin_amdgcn_s_setprio(0);
    }

    // ---------- epilogue: fully in-register LSTM pointwise
    const float b0 = bias[f], b1 = bias[64 + f], b2 = bias[128 + f], b3 = bias[192 + f];

#pragma unroll
    for (int mf = 0; mf < 8; ++mf) {
        const int gy = y0 + wm * 2 + (mf >> 2);
        const int xb = (mf & 3) * 16 + lg * 4;
        const size_t hbase = ((((size_t)bb * NH + gy) * NW + xb) << 6) + f;
        f16x4v cn4, hn4;
#pragma unroll
        for (int j = 0; j < 4; ++j) {
            const float zi  = acc[mf][0][j] + b0;
            const float zfv = acc[mf][1][j] + b1;
            const float zc  = acc[mf][2][j] + b2;
            const float zo  = acc[mf][3][j] + b3;
            const float ig = hsig(zi), fg = hsig(zfv), og = hsig(zo);
            const float cn = fg * (float)cp[mf][j] + ig * ftanh(zc);
            cn4[j] = (f16)cn;
            const float hn = og * ftanh(cn);
            hn4[j] = (f16)hn;
            hout[(size_t)bb * OUT_BSTRIDE + (((size_t)gy * NW + xb + j) << 6) + f] = hn;
        }
        if (!last) {
            *(f16x4v*)&cbuf[(((size_t)bb * NH + gy) * NF + f) * 64 + xb] = cn4;
#pragma unroll
            for (int j = 0; j < 4; ++j)
                h2out[hbase + (size_t)j * 64] = hn4[j];
        }
    }
}

extern "C" void kernel_launch(void* const* d_in, const int* in_sizes, int n_in,
                              void* d_out, int out_size, void* d_ws, size_t ws_size,
                              hipStream_t stream) {
    const float* h0    = (const float*)d_in[1];
    const float* c0    = (const float*)d_in[2];
    const float* kern  = (const float*)d_in[3];
    const float* rkern = (const float*)d_in[4];
    const float* bias  = (const float*)d_in[5];
    float* out = (float*)d_out;

    f16* wf2   = (f16*)d_ws;                                  // 4.7 MB (hi only)
    f16* h2a   = wf2 + (size_t)NT * WSTEP * 8;                // 8.4 MB
    f16* h2b   = h2a + (size_t)NB * HWF;                      // 8.4 MB
    f16* cbuf  = h2b + (size_t)NB * HWF;                      // 8.4 MB (f16 c, [b][y][f][x])

    prologue_all<<<dim3(9344), 256, 0, stream>>>(kern, rkern, wf2, h0, h2a, c0, cbuf);

    for (int t = 0; t < NT; ++t) {
        const f16* hin = (t & 1) ? h2b : h2a;
        f16* hnx       = (t & 1) ? h2a : h2b;
        convlstm_mfma_step<<<dim3(256), 512, 0, stream>>>(
            hin, hnx, cbuf,
            out + (size_t)t * HWF,
            wf2 + (size_t)t * WSTEP * 8,
            bias + t * NG,
            (t == NT - 1) ? 1 : 0);
    }
}